// Round 3
// baseline (1086.796 us; speedup 1.0000x reference)
//
#include <hip/hip_runtime.h>
#include <math.h>

#define T_LEN 256
#define B_SZ  64
#define IN_D  512
#define H_D   1024
#define G4    4096   // 4*H

typedef float  f32x4 __attribute__((ext_vector_type(4)));
typedef short  s16x8 __attribute__((ext_vector_type(8)));
typedef unsigned int u32x4 __attribute__((ext_vector_type(4)));
typedef unsigned short u16;
typedef unsigned int   u32;

// ---------- helpers ----------
__device__ __forceinline__ void gl_lds16(const void* g, void* l) {
  __builtin_amdgcn_global_load_lds(
      (const __attribute__((address_space(1))) unsigned int*)g,
      (__attribute__((address_space(3))) unsigned int*)l, 16, 0, 0);
}

__device__ __forceinline__ u16 f2bf(float f) {
  union { float f; unsigned u; } v; v.f = f;
  unsigned x = v.u;
  unsigned r = (x + 0x7fffu + ((x >> 16) & 1u)) >> 16;  // RNE
  return (u16)r;
}
__device__ __forceinline__ float bf2f(u16 b) {
  union { unsigned u; float f; } v; v.u = ((unsigned)b) << 16;
  return v.f;
}
__device__ __forceinline__ float sigm(float x) {
  return 1.0f / (1.0f + __expf(-x));
}
// fast tanh via exp2-backed __expf; saturates correctly at +-inf
__device__ __forceinline__ float tanh_f(float x) {
  float e = __expf(2.0f * x);
  return 1.0f - 2.0f / (e + 1.0f);
}

// ---------- fp32 -> bf16 convert ----------
__global__ void cvt_f32_bf16(const float* __restrict__ src, u16* __restrict__ dst, int n) {
  int i = blockIdx.x * blockDim.x + threadIdx.x;
  int stride = gridDim.x * blockDim.x;
  for (; i < n; i += stride) dst[i] = f2bf(src[i]);
}

// ---------- sentinel fill for hs (sc1 write-through: NO per-XCD L2 lines ever) ----
// h = sigm*tanh is finite in (-1,1); a data u32 (two bf16) can never be 0xFFFFFFFF
// (NaN|NaN). So 0xFFFFFFFF words mean "not yet written" -- consumers poll data
// directly, no flags, no producer-side drain.
__global__ void fill_sentinel(u32* __restrict__ p, int n4) {
  int i = blockIdx.x * blockDim.x + threadIdx.x;
  int stride = gridDim.x * blockDim.x;
  u32x4 s = {0xFFFFFFFFu, 0xFFFFFFFFu, 0xFFFFFFFFu, 0xFFFFFFFFu};
  for (; i < n4; i += stride) {
    u32* dst = p + (size_t)i * 4;
    asm volatile("global_store_dwordx4 %0, %1, off sc1" :: "v"(dst), "v"(s) : "memory");
  }
}

// ---------- generic bf16 GEMM: C[M,N] = A[M,K] * B[N,K]^T (+epilogue) ----------
// 128x128 block tile, BK=64, 4 waves (2x2), 16x16x32 MFMA, global_load_lds staging
// with XOR-row chunk swizzle for conflict-free ds_read_b128 fragment loads.
// EPI 0: out bf16 = acc + bias[col] + (row<64 ? img[row][col&1023] : 0)   (xproj)
// EPI 1: out f32  = acc + bias[col]                                       (logits)
template<int KD, int EPI>
__launch_bounds__(256)
__global__ void gemm_bt(const u16* __restrict__ A, const u16* __restrict__ Bm,
                        const float* __restrict__ bias, const float* __restrict__ img,
                        u16* __restrict__ Cb, float* __restrict__ Cf, int Ncols) {
  __shared__ u16 sA[128 * 64];
  __shared__ u16 sB[128 * 64];
  const int tid  = threadIdx.x;
  const int wave = tid >> 6, lane = tid & 63;
  const int wm = wave >> 1, wn = wave & 1;
  const int mBase = blockIdx.y * 128;
  const int nBase = blockIdx.x * 128;

  f32x4 acc[4][4] = {};

  for (int k0 = 0; k0 < KD; k0 += 64) {
#pragma unroll
    for (int it = 0; it < 4; ++it) {
      int s = it * 256 + tid;
      int row = s >> 3, c = s & 7;
      int gc = c ^ (row & 7);
      const u16* ga = A  + (size_t)(mBase + row) * KD + k0 + gc * 8;
      const u16* gb = Bm + (size_t)(nBase + row) * KD + k0 + gc * 8;
      gl_lds16(ga, &sA[(it * 256 + wave * 64) * 8]);
      gl_lds16(gb, &sB[(it * 256 + wave * 64) * 8]);
    }
    __syncthreads();

    const int q = lane >> 4, rl = lane & 15;
#pragma unroll
    for (int ks = 0; ks < 64; ks += 32) {
      s16x8 af[4], bfr[4];
      int gcb = (ks >> 3) + q;
#pragma unroll
      for (int i = 0; i < 4; ++i) {
        int rowA = wm * 64 + i * 16 + rl;
        af[i]  = *(const s16x8*)&sA[rowA * 64 + (gcb ^ (rowA & 7)) * 8];
        int rowB = wn * 64 + i * 16 + rl;
        bfr[i] = *(const s16x8*)&sB[rowB * 64 + (gcb ^ (rowB & 7)) * 8];
      }
#pragma unroll
      for (int i = 0; i < 4; ++i)
#pragma unroll
        for (int j = 0; j < 4; ++j)
          acc[i][j] = __builtin_amdgcn_mfma_f32_16x16x32_bf16(af[i], bfr[j], acc[i][j], 0, 0, 0);
    }
    __syncthreads();
  }

  // epilogue: C/D layout col=lane&15, row=(lane>>4)*4+r
#pragma unroll
  for (int i = 0; i < 4; ++i) {
    int rbase = mBase + wm * 64 + i * 16 + ((lane >> 4) << 2);
#pragma unroll
    for (int j = 0; j < 4; ++j) {
      int col = nBase + wn * 64 + j * 16 + (lane & 15);
      float bc = bias[col];
#pragma unroll
      for (int r = 0; r < 4; ++r) {
        int row = rbase + r;
        float v = acc[i][j][r] + bc;
        if (EPI == 0) {
          if (row < B_SZ) v += img[row * H_D + (col & (H_D - 1))];
          Cb[(size_t)row * Ncols + col] = f2bf(v);
        } else {
          Cf[(size_t)row * Ncols + col] = v;
        }
      }
    }
  }
}

// ---------- persistent LSTM recurrence ----------
// grid = 256 blocks = 4 batch-groups x 64 column-slices; block = 256 thr (4 waves).
// WG (grp,wg): batches [grp*16,+16), h-columns [wg*16,+16).
// R3 structure: NO LDS h-path at all. Each wave loads its MFMA A-fragments
// DIRECTLY from global hs with per-lane addresses matching the 16x16x32 A layout
// (lane(rl,q) holds h[batch=rl][k0+q*8..+8], 16B contiguous). The loaded dwordx4
// registers feed MFMA with zero repacking. Wave w's K-quarter = cols [256w,+256)
// = producers wgs [16w,+16) only -> per-wave tail over 16 producers, not 64.
// Sentinel poll (0xFFFFFFFF) validates data in-register; retry reloads only
// missing fragments. Cross-wave gate reduction via double-buffered sGp[t&1]
// -> exactly ONE __syncthreads per step (parity makes reuse provably safe:
// a wave can only reach the next same-parity write after all waves passed the
// intervening barrier, which is after all sGp reads).
__launch_bounds__(256, 1)
__global__ void lstm_rec(const u16* __restrict__ WhhB, const u16* __restrict__ xproj,
                         const float* __restrict__ bhh, u32* __restrict__ hs32) {
  __shared__ float sGp[2][16][16][17];   // 34 KB, partial gates [parity][wave*4+g][batch][col]

  const int tid  = threadIdx.x;
  const int wave = tid >> 6, lane = tid & 63;
  const int grp = blockIdx.x >> 6;       // 0..3
  const int wg  = blockIdx.x & 63;       // 0..63
  const int bBase = grp * 16;
  const int colBase = wg * 16;
  const int q = lane >> 4, rl = lane & 15;

  // ---- hoist this wave's Whh K-slice into registers: wf[gate][m] covers
  // row (gate*H + colBase + rl), k = wave*256 + m*32 + q*8 .. +8
  s16x8 wf[4][8];
  {
    const u16* wb = WhhB + (size_t)(colBase + rl) * H_D + wave * 256 + q * 8;
#pragma unroll
    for (int g = 0; g < 4; ++g)
#pragma unroll
      for (int m = 0; m < 8; ++m)
        wf[g][m] = *(const s16x8*)(wb + (size_t)g * H_D * H_D + m * 32);
  }

  float cst = 0.f;
  const int ub = tid >> 4, uc = tid & 15;     // local (batch, col) for cell update
  const int gb = bBase + ub;
  const int gcol = colBase + uc;
  const float bh_i = bhh[0 * H_D + gcol], bh_f = bhh[1 * H_D + gcol];
  const float bh_g = bhh[2 * H_D + gcol], bh_o = bhh[3 * H_D + gcol];

  for (int t = 0; t < T_LEN; ++t) {
    // xproj loads first (plain cached loads, latency hides under the poll wait;
    // kept BEFORE the poll asm so compiler-inserted waitcnt ordering stays sound)
    const u16* xp = xproj + ((size_t)t * B_SZ + gb) * G4;
    float gi_ = bf2f(xp[0 * H_D + gcol]) + bh_i;
    float gf_ = bf2f(xp[1 * H_D + gcol]) + bh_f;
    float gg_ = bf2f(xp[2 * H_D + gcol]) + bh_g;
    float go_ = bf2f(xp[3 * H_D + gcol]) + bh_o;

    if (t > 0) {
      // direct A-fragment poll loads: lane(rl,q), fragment m reads 16B at
      // h[t-1][bBase+rl][wave*256 + m*32 + q*8]  (u32 units: rl*512+wave*128+m*16+q*4)
      u32x4 v[8];
      const u32* hp = hs32 + (size_t)(t - 1) * B_SZ * 512 + (size_t)bBase * 512
                    + rl * 512 + wave * 128 + q * 4;
#pragma unroll
      for (int m = 0; m < 8; ++m)
        asm volatile("global_load_dwordx4 %0, %1, off sc1"
                     : "=v"(v[m]) : "v"(hp + m * 16) : "memory");
      asm volatile("s_waitcnt vmcnt(0)" ::: "memory");
      __builtin_amdgcn_sched_barrier(0);
      for (;;) {
        u32 bad = 0;
#pragma unroll
        for (int m = 0; m < 8; ++m) {
          bool st = (v[m][0] == 0xFFFFFFFFu) | (v[m][1] == 0xFFFFFFFFu) |
                    (v[m][2] == 0xFFFFFFFFu) | (v[m][3] == 0xFFFFFFFFu);
          bad |= st ? (1u << m) : 0u;
        }
        if (!__any((int)bad)) break;
#pragma unroll
        for (int m = 0; m < 8; ++m)
          if (bad & (1u << m))
            asm volatile("global_load_dwordx4 %0, %1, off sc1"
                         : "=v"(v[m]) : "v"(hp + m * 16) : "memory");
        asm volatile("s_waitcnt vmcnt(0)" ::: "memory");
        __builtin_amdgcn_sched_barrier(0);
      }

      // MFMA: loaded registers ARE the A-fragments; 1 fragment feeds 4 gates.
      f32x4 a0 = {}, a1 = {}, a2 = {}, a3 = {};
#pragma unroll
      for (int m = 0; m < 8; ++m) {
        s16x8 afr = *(const s16x8*)&v[m];
        a0 = __builtin_amdgcn_mfma_f32_16x16x32_bf16(afr, wf[0][m], a0, 0, 0, 0);
        a1 = __builtin_amdgcn_mfma_f32_16x16x32_bf16(afr, wf[1][m], a1, 0, 0, 0);
        a2 = __builtin_amdgcn_mfma_f32_16x16x32_bf16(afr, wf[2][m], a2, 0, 0, 0);
        a3 = __builtin_amdgcn_mfma_f32_16x16x32_bf16(afr, wf[3][m], a3, 0, 0, 0);
      }
      // partial gate sums: C/D layout col=lane&15, row=(lane>>4)*4+r
      const int p = t & 1;
#pragma unroll
      for (int r = 0; r < 4; ++r) {
        int row = (lane >> 4) * 4 + r;
        sGp[p][wave * 4 + 0][row][lane & 15] = a0[r];
        sGp[p][wave * 4 + 1][row][lane & 15] = a1[r];
        sGp[p][wave * 4 + 2][row][lane & 15] = a2[r];
        sGp[p][wave * 4 + 3][row][lane & 15] = a3[r];
      }
      __syncthreads();   // the ONLY barrier per step
      gi_ += sGp[p][0][ub][uc] + sGp[p][4][ub][uc] + sGp[p][8][ub][uc]  + sGp[p][12][ub][uc];
      gf_ += sGp[p][1][ub][uc] + sGp[p][5][ub][uc] + sGp[p][9][ub][uc]  + sGp[p][13][ub][uc];
      gg_ += sGp[p][2][ub][uc] + sGp[p][6][ub][uc] + sGp[p][10][ub][uc] + sGp[p][14][ub][uc];
      go_ += sGp[p][3][ub][uc] + sGp[p][7][ub][uc] + sGp[p][11][ub][uc] + sGp[p][15][ub][uc];
    }

    // cell update: one (batch,col) per thread
    cst = sigm(gf_) * cst + sigm(gi_) * tanh_f(gg_);
    float h = sigm(go_) * tanh_f(cst);

    // pack 8 cols -> dwordx4, fire-and-forget write-through to LLC
    u32 b = f2bf(h);
    u32 p1 = (u32)__shfl_xor((int)b, 1);
    u32 w0 = b | (p1 << 16);                       // cols (uc, uc+1) on even lanes
    u32 w1 = (u32)__shfl_xor((int)w0, 2);          // cols (uc+2, uc+3)
    u32 w2 = (u32)__shfl_xor((int)w0, 4);          // cols (uc+4, uc+5)
    u32 w3 = (u32)__shfl_xor((int)w1, 4);          // cols (uc+6, uc+7)
    if ((tid & 7) == 0) {
      u32x4 pk = {w0, w1, w2, w3};
      u32* dst = hs32 + ((size_t)t * B_SZ + gb) * 512 + (gcol >> 1);
      asm volatile("global_store_dwordx4 %0, %1, off sc1"
                   :: "v"(dst), "v"(pk) : "memory");
    }
    // no drain, no flag, no barrier: consumers poll the data itself
  }
  asm volatile("s_waitcnt vmcnt(0)" ::: "memory");  // final stores acked before end
}

// ---------- in-place log_softmax over rows of 512 ----------
__launch_bounds__(256)
__global__ void logsoftmax_rows(float* __restrict__ out) {
  __shared__ float red[8];
  float* p = out + (size_t)blockIdx.x * IN_D;
  const int tid = threadIdx.x;
  float v0 = p[tid], v1 = p[tid + 256];
  float m = fmaxf(v0, v1);
#pragma unroll
  for (int off = 32; off > 0; off >>= 1) m = fmaxf(m, __shfl_down(m, off));
  if ((tid & 63) == 0) red[tid >> 6] = m;
  __syncthreads();
  m = fmaxf(fmaxf(red[0], red[1]), fmaxf(red[2], red[3]));
  float e = __expf(v0 - m) + __expf(v1 - m);
#pragma unroll
  for (int off = 32; off > 0; off >>= 1) e += __shfl_down(e, off);
  if ((tid & 63) == 0) red[4 + (tid >> 6)] = e;
  __syncthreads();
  float ls = m + logf(red[4] + red[5] + red[6] + red[7]);
  p[tid] = v0 - ls;
  p[tid + 256] = v1 - ls;
}

// ---------- launch ----------
extern "C" void kernel_launch(void* const* d_in, const int* in_sizes, int n_in,
                              void* d_out, int out_size, void* d_ws, size_t ws_size,
                              hipStream_t stream) {
  const float* inp  = (const float*)d_in[0];
  const float* img  = (const float*)d_in[1];
  const float* Wxh  = (const float*)d_in[2];
  const float* bxh  = (const float*)d_in[3];
  const float* Whh  = (const float*)d_in[4];
  const float* bhh  = (const float*)d_in[5];
  const float* Wout = (const float*)d_in[6];
  const float* bout = (const float*)d_in[7];
  float* out = (float*)d_out;

  char* ws = (char*)d_ws;
  u16* inpB   = (u16*)(ws);                    // 16 MB  (256*64*512)
  u16* WxhB   = (u16*)(ws + 16777216);         // 4 MB   (4096*512)
  u16* WhhB   = (u16*)(ws + 20971520);         // 8 MB   (4096*1024)
  u16* WoutB  = (u16*)(ws + 29360128);         // 1 MB   (512*1024)
  u16* xprojB = (u16*)(ws + 30408704);         // 128 MB (16384*4096)
  u16* hsB    = (u16*)(ws + 164626432);        // 32 MB  (256*64*1024)

  // sentinel-fill hs FIRST (sc1: never creates per-XCD L2 lines for hsB)
  fill_sentinel<<<2048, 256, 0, stream>>>((u32*)hsB, T_LEN * B_SZ * 512 / 4);

  cvt_f32_bf16<<<2048, 256, 0, stream>>>(inp,  inpB,  T_LEN * B_SZ * IN_D);
  cvt_f32_bf16<<<2048, 256, 0, stream>>>(Wxh,  WxhB,  G4 * IN_D);
  cvt_f32_bf16<<<2048, 256, 0, stream>>>(Whh,  WhhB,  G4 * H_D);
  cvt_f32_bf16<<<2048, 256, 0, stream>>>(Wout, WoutB, IN_D * H_D);

  // xproj = inp@Wxh^T + bxh (+ img4 at t=0), bf16 out
  gemm_bt<IN_D, 0><<<dim3(G4 / 128, 16384 / 128), 256, 0, stream>>>(
      inpB, WxhB, bxh, img, xprojB, nullptr, G4);

  lstm_rec<<<256, 256, 0, stream>>>(WhhB, xprojB, bhh, (u32*)hsB);

  // logits = hs@Wout^T + bout, f32 into d_out
  gemm_bt<H_D, 1><<<dim3(IN_D / 128, 16384 / 128), 256, 0, stream>>>(
      hsB, WoutB, bout, nullptr, nullptr, out, IN_D);

  logsoftmax_rows<<<16384, 256, 0, stream>>>(out);
}

// Round 9
// 1020.836 us; speedup vs baseline: 1.0646x; 1.0646x over previous
//
#include <hip/hip_runtime.h>
#include <math.h>

#define T_LEN 256
#define B_SZ  64
#define IN_D  512
#define H_D   1024
#define G4    4096   // 4*H

typedef float  f32x4 __attribute__((ext_vector_type(4)));
typedef short  s16x8 __attribute__((ext_vector_type(8)));
typedef unsigned int u32x4 __attribute__((ext_vector_type(4)));
typedef unsigned short u16;
typedef unsigned int   u32;

// ---------- helpers ----------
__device__ __forceinline__ void gl_lds16(const void* g, void* l) {
  __builtin_amdgcn_global_load_lds(
      (const __attribute__((address_space(1))) unsigned int*)g,
      (__attribute__((address_space(3))) unsigned int*)l, 16, 0, 0);
}

__device__ __forceinline__ u16 f2bf(float f) {
  union { float f; unsigned u; } v; v.f = f;
  unsigned x = v.u;
  unsigned r = (x + 0x7fffu + ((x >> 16) & 1u)) >> 16;  // RNE
  return (u16)r;
}
__device__ __forceinline__ float bf2f(u16 b) {
  union { unsigned u; float f; } v; v.u = ((unsigned)b) << 16;
  return v.f;
}
__device__ __forceinline__ float sigm(float x) {
  return 1.0f / (1.0f + __expf(-x));
}
// fast tanh via exp2-backed __expf; saturates correctly at +-inf
__device__ __forceinline__ float tanh_f(float x) {
  float e = __expf(2.0f * x);
  return 1.0f - 2.0f / (e + 1.0f);
}

// ---------- fp32 -> bf16 convert ----------
__global__ void cvt_f32_bf16(const float* __restrict__ src, u16* __restrict__ dst, int n) {
  int i = blockIdx.x * blockDim.x + threadIdx.x;
  int stride = gridDim.x * blockDim.x;
  for (; i < n; i += stride) dst[i] = f2bf(src[i]);
}

// ---------- sentinel fill for hs (sc1 write-through: NO per-XCD L2 lines ever) ----
// h = sigm*tanh is finite in (-1,1); a data u32 (two bf16) can never be 0xFFFFFFFF
// (NaN|NaN). So 0xFFFFFFFF words mean "not yet written" -- consumers poll data
// directly, no flags, no producer-side drain.
__global__ void fill_sentinel(u32* __restrict__ p, int n4) {
  int i = blockIdx.x * blockDim.x + threadIdx.x;
  int stride = gridDim.x * blockDim.x;
  u32x4 s = {0xFFFFFFFFu, 0xFFFFFFFFu, 0xFFFFFFFFu, 0xFFFFFFFFu};
  for (; i < n4; i += stride) {
    u32* dst = p + (size_t)i * 4;
    asm volatile("global_store_dwordx4 %0, %1, off sc1" :: "v"(dst), "v"(s) : "memory");
  }
}

// ---------- generic bf16 GEMM: C[M,N] = A[M,K] * B[N,K]^T (+epilogue) ----------
// 128x128 block tile, BK=64, 4 waves (2x2), 16x16x32 MFMA, global_load_lds staging
// with XOR-row chunk swizzle for conflict-free ds_read_b128 fragment loads.
// EPI 0: out bf16 = acc + bias[col] + (row<64 ? img[row][col&1023] : 0)   (xproj)
// EPI 1: out f32  = acc + bias[col]                                       (logits)
template<int KD, int EPI>
__launch_bounds__(256)
__global__ void gemm_bt(const u16* __restrict__ A, const u16* __restrict__ Bm,
                        const float* __restrict__ bias, const float* __restrict__ img,
                        u16* __restrict__ Cb, float* __restrict__ Cf, int Ncols) {
  __shared__ u16 sA[128 * 64];
  __shared__ u16 sB[128 * 64];
  const int tid  = threadIdx.x;
  const int wave = tid >> 6, lane = tid & 63;
  const int wm = wave >> 1, wn = wave & 1;
  const int mBase = blockIdx.y * 128;
  const int nBase = blockIdx.x * 128;

  f32x4 acc[4][4] = {};

  for (int k0 = 0; k0 < KD; k0 += 64) {
#pragma unroll
    for (int it = 0; it < 4; ++it) {
      int s = it * 256 + tid;
      int row = s >> 3, c = s & 7;
      int gc = c ^ (row & 7);
      const u16* ga = A  + (size_t)(mBase + row) * KD + k0 + gc * 8;
      const u16* gb = Bm + (size_t)(nBase + row) * KD + k0 + gc * 8;
      gl_lds16(ga, &sA[(it * 256 + wave * 64) * 8]);
      gl_lds16(gb, &sB[(it * 256 + wave * 64) * 8]);
    }
    __syncthreads();

    const int q = lane >> 4, rl = lane & 15;
#pragma unroll
    for (int ks = 0; ks < 64; ks += 32) {
      s16x8 af[4], bfr[4];
      int gcb = (ks >> 3) + q;
#pragma unroll
      for (int i = 0; i < 4; ++i) {
        int rowA = wm * 64 + i * 16 + rl;
        af[i]  = *(const s16x8*)&sA[rowA * 64 + (gcb ^ (rowA & 7)) * 8];
        int rowB = wn * 64 + i * 16 + rl;
        bfr[i] = *(const s16x8*)&sB[rowB * 64 + (gcb ^ (rowB & 7)) * 8];
      }
#pragma unroll
      for (int i = 0; i < 4; ++i)
#pragma unroll
        for (int j = 0; j < 4; ++j)
          acc[i][j] = __builtin_amdgcn_mfma_f32_16x16x32_bf16(af[i], bfr[j], acc[i][j], 0, 0, 0);
    }
    __syncthreads();
  }

  // epilogue: C/D layout col=lane&15, row=(lane>>4)*4+r
#pragma unroll
  for (int i = 0; i < 4; ++i) {
    int rbase = mBase + wm * 64 + i * 16 + ((lane >> 4) << 2);
#pragma unroll
    for (int j = 0; j < 4; ++j) {
      int col = nBase + wn * 64 + j * 16 + (lane & 15);
      float bc = bias[col];
#pragma unroll
      for (int r = 0; r < 4; ++r) {
        int row = rbase + r;
        float v = acc[i][j][r] + bc;
        if (EPI == 0) {
          if (row < B_SZ) v += img[row * H_D + (col & (H_D - 1))];
          Cb[(size_t)row * Ncols + col] = f2bf(v);
        } else {
          Cf[(size_t)row * Ncols + col] = v;
        }
      }
    }
  }
}

// ---------- persistent LSTM recurrence ----------
// grid = 256 blocks = 4 batch-groups x 64 column-slices; block = 256 thr (4 waves)
// -- the R2 kernel (verified passing 3x) with ONE structural change:
// WAVE-LOCAL K-QUARTERS. Wave w loads, scatters, and MFMA-reads ONLY sH columns
// [256w,+256): sH becomes wave-private, so
//  * B1 (scatter->read barrier) is DELETED -- per-wave DS program order covers
//    the write->read hazard (no cross-wave sH sharing at all);
//  * wave w's poll gates on only its 16 producer wgs [16w,+16) instead of all
//    64 -- the per-step tail term shrinks and wave skew overlaps with compute;
//  * sGp is parity double-buffered (verified in R3's passing run) so B2 is the
//    ONLY barrier per step. A slow reader of sGp[p] at step t is protected from
//    step-(t+2) writers by B2(t+1), which writers must pass and readers reach
//    only after their t reads.
// Transport identical to R2: fire-and-forget sc1 stores, sentinel (0xFFFFFFFF)
// data-polling sc1 loads, no flags, no drain, MALL-coherent everywhere.
__launch_bounds__(256, 1)
__global__ void lstm_rec(const u16* __restrict__ WhhB, const u16* __restrict__ xproj,
                         const float* __restrict__ bhh, u32* __restrict__ hs32) {
  __shared__ u16  sH[16 * 1024];         // 32 KB, h tile (swizzled, wave-private quarters)
  __shared__ float sGp[2][16][16][17];   // 34 KB, partial gates [parity][wave*4+g][batch][col]

  const int tid  = threadIdx.x;
  const int wave = tid >> 6, lane = tid & 63;
  const int grp = blockIdx.x >> 6;       // 0..3
  const int wg  = blockIdx.x & 63;       // 0..63
  const int bBase = grp * 16;
  const int colBase = wg * 16;
  const int q = lane >> 4, rl = lane & 15;

  // ---- hoist this wave's Whh K-slice into registers: wf[gate][m] covers
  // row (gate*H + colBase + rl), k = wave*256 + m*32 + q*8 .. +8
  s16x8 wf[4][8];
  {
    const u16* wb = WhhB + (size_t)(colBase + rl) * H_D + wave * 256 + q * 8;
#pragma unroll
    for (int g = 0; g < 4; ++g)
#pragma unroll
      for (int m = 0; m < 8; ++m)
        wf[g][m] = *(const s16x8*)(wb + (size_t)g * H_D * H_D + m * 32);
  }

  float cst = 0.f;
  const int ub = tid >> 4, uc = tid & 15;     // local (batch, col) for cell update
  const int gb = bBase + ub;
  const int gcol = colBase + uc;
  const float bh_i = bhh[0 * H_D + gcol], bh_f = bhh[1 * H_D + gcol];
  const float bh_g = bhh[2 * H_D + gcol], bh_o = bhh[3 * H_D + gcol];

  for (int t = 0; t < T_LEN; ++t) {
    // xproj loads first (plain cached loads; latency hides under the data poll)
    const u16* xp = xproj + ((size_t)t * B_SZ + gb) * G4;
    float gi_ = bf2f(xp[0 * H_D + gcol]) + bh_i;
    float gf_ = bf2f(xp[1 * H_D + gcol]) + bh_f;
    float gg_ = bf2f(xp[2 * H_D + gcol]) + bh_g;
    float go_ = bf2f(xp[3 * H_D + gcol]) + bh_o;

    if (t > 0) {
      // WAVE-LOCAL bulk-load: wave w reads its K-quarter of the group's h[t-1]
      // slab -- 16 batches x 256 cols = 8 KB = 512 chunks, 8/lane, coalesced
      // (lanes 0-31 cover one row's 32-chunk span = 512B contiguous).
      // chunk id within quarter: k = j*64+lane -> row=k>>5, c=wave*32+(k&31).
      u32x4 v[8];
      const u32* hp = hs32 + (size_t)(t - 1) * B_SZ * 512 + (size_t)bBase * 512;
#pragma unroll
      for (int j = 0; j < 8; ++j) {
        int k = j * 64 + lane;
        int row = k >> 5, c = wave * 32 + (k & 31);
        const u32* p = hp + row * 512 + c * 4;
        asm volatile("global_load_dwordx4 %0, %1, off sc1"
                     : "=v"(v[j]) : "v"(p) : "memory");
      }
      asm volatile("s_waitcnt vmcnt(0)" ::: "memory");
      __builtin_amdgcn_sched_barrier(0);
      for (;;) {
        u32 bad = 0;
#pragma unroll
        for (int j = 0; j < 8; ++j) {
          bool st = (v[j][0] == 0xFFFFFFFFu) | (v[j][1] == 0xFFFFFFFFu) |
                    (v[j][2] == 0xFFFFFFFFu) | (v[j][3] == 0xFFFFFFFFu);
          bad |= st ? (1u << j) : 0u;
        }
        if (!__any((int)bad)) break;   // per-wave exit: only this wave's 16 producers
#pragma unroll
        for (int j = 0; j < 8; ++j) {
          if (bad & (1u << j)) {
            int k = j * 64 + lane;
            int row = k >> 5, c = wave * 32 + (k & 31);
            const u32* p = hp + row * 512 + c * 4;
            asm volatile("global_load_dwordx4 %0, %1, off sc1"
                         : "=v"(v[j]) : "v"(p) : "memory");
          }
        }
        asm volatile("s_waitcnt vmcnt(0)" ::: "memory");
        __builtin_amdgcn_sched_barrier(0);
      }
      // scatter into swizzled sH -- wave-private quarter, NO barrier needed:
      // the only reader of these addresses is this same wave (DS program order)
#pragma unroll
      for (int j = 0; j < 8; ++j) {
        int k = j * 64 + lane;
        int row = k >> 5, c = wave * 32 + (k & 31);
        *(s16x8*)&sH[row * 1024 + (c ^ (row & 7)) * 8] = *(s16x8*)&v[j];
      }

      // MFMA: this wave's K-quarter, all 4 gates; 1 A-read feeds 4 MFMAs.
      f32x4 a0 = {}, a1 = {}, a2 = {}, a3 = {};
#pragma unroll
      for (int m = 0; m < 8; ++m) {
        int chunk = wave * 32 + m * 4 + q;
        s16x8 afr = *(const s16x8*)&sH[rl * 1024 + ((chunk ^ (rl & 7))) * 8];
        a0 = __builtin_amdgcn_mfma_f32_16x16x32_bf16(afr, wf[0][m], a0, 0, 0, 0);
        a1 = __builtin_amdgcn_mfma_f32_16x16x32_bf16(afr, wf[1][m], a1, 0, 0, 0);
        a2 = __builtin_amdgcn_mfma_f32_16x16x32_bf16(afr, wf[2][m], a2, 0, 0, 0);
        a3 = __builtin_amdgcn_mfma_f32_16x16x32_bf16(afr, wf[3][m], a3, 0, 0, 0);
      }
      // partial gate sums: C/D layout col=lane&15, row=(lane>>4)*4+r
      const int p = t & 1;
#pragma unroll
      for (int r = 0; r < 4; ++r) {
        int row = (lane >> 4) * 4 + r;
        sGp[p][wave * 4 + 0][row][lane & 15] = a0[r];
        sGp[p][wave * 4 + 1][row][lane & 15] = a1[r];
        sGp[p][wave * 4 + 2][row][lane & 15] = a2[r];
        sGp[p][wave * 4 + 3][row][lane & 15] = a3[r];
      }
      __syncthreads();   // B2: the ONLY barrier per step
      gi_ += sGp[p][0][ub][uc] + sGp[p][4][ub][uc] + sGp[p][8][ub][uc]  + sGp[p][12][ub][uc];
      gf_ += sGp[p][1][ub][uc] + sGp[p][5][ub][uc] + sGp[p][9][ub][uc]  + sGp[p][13][ub][uc];
      gg_ += sGp[p][2][ub][uc] + sGp[p][6][ub][uc] + sGp[p][10][ub][uc] + sGp[p][14][ub][uc];
      go_ += sGp[p][3][ub][uc] + sGp[p][7][ub][uc] + sGp[p][11][ub][uc] + sGp[p][15][ub][uc];
    }

    // cell update: one (batch,col) per thread
    cst = sigm(gf_) * cst + sigm(gi_) * tanh_f(gg_);
    float h = sigm(go_) * tanh_f(cst);

    // pack 8 cols -> dwordx4, fire-and-forget write-through to LLC
    u32 b = f2bf(h);
    u32 p1 = (u32)__shfl_xor((int)b, 1);
    u32 w0 = b | (p1 << 16);                       // cols (uc, uc+1) on even lanes
    u32 w1 = (u32)__shfl_xor((int)w0, 2);          // cols (uc+2, uc+3)
    u32 w2 = (u32)__shfl_xor((int)w0, 4);          // cols (uc+4, uc+5)
    u32 w3 = (u32)__shfl_xor((int)w1, 4);          // cols (uc+6, uc+7)
    if ((tid & 7) == 0) {
      u32x4 pk = {w0, w1, w2, w3};
      u32* dst = hs32 + ((size_t)t * B_SZ + gb) * 512 + (gcol >> 1);
      asm volatile("global_store_dwordx4 %0, %1, off sc1"
                   :: "v"(dst), "v"(pk) : "memory");
    }
    // no drain, no flag, no barrier: consumers poll the data itself
  }
  asm volatile("s_waitcnt vmcnt(0)" ::: "memory");  // final stores acked before end
}

// ---------- in-place log_softmax over rows of 512 ----------
__launch_bounds__(256)
__global__ void logsoftmax_rows(float* __restrict__ out) {
  __shared__ float red[8];
  float* p = out + (size_t)blockIdx.x * IN_D;
  const int tid = threadIdx.x;
  float v0 = p[tid], v1 = p[tid + 256];
  float m = fmaxf(v0, v1);
#pragma unroll
  for (int off = 32; off > 0; off >>= 1) m = fmaxf(m, __shfl_down(m, off));
  if ((tid & 63) == 0) red[tid >> 6] = m;
  __syncthreads();
  m = fmaxf(fmaxf(red[0], red[1]), fmaxf(red[2], red[3]));
  float e = __expf(v0 - m) + __expf(v1 - m);
#pragma unroll
  for (int off = 32; off > 0; off >>= 1) e += __shfl_down(e, off);
  if ((tid & 63) == 0) red[4 + (tid >> 6)] = e;
  __syncthreads();
  float ls = m + logf(red[4] + red[5] + red[6] + red[7]);
  p[tid] = v0 - ls;
  p[tid + 256] = v1 - ls;
}

// ---------- launch ----------
extern "C" void kernel_launch(void* const* d_in, const int* in_sizes, int n_in,
                              void* d_out, int out_size, void* d_ws, size_t ws_size,
                              hipStream_t stream) {
  const float* inp  = (const float*)d_in[0];
  const float* img  = (const float*)d_in[1];
  const float* Wxh  = (const float*)d_in[2];
  const float* bxh  = (const float*)d_in[3];
  const float* Whh  = (const float*)d_in[4];
  const float* bhh  = (const float*)d_in[5];
  const float* Wout = (const float*)d_in[6];
  const float* bout = (const float*)d_in[7];
  float* out = (float*)d_out;

  char* ws = (char*)d_ws;
  u16* inpB   = (u16*)(ws);                    // 16 MB  (256*64*512)
  u16* WxhB   = (u16*)(ws + 16777216);         // 4 MB   (4096*512)
  u16* WhhB   = (u16*)(ws + 20971520);         // 8 MB   (4096*1024)
  u16* WoutB  = (u16*)(ws + 29360128);         // 1 MB   (512*1024)
  u16* xprojB = (u16*)(ws + 30408704);         // 128 MB (16384*4096)
  u16* hsB    = (u16*)(ws + 164626432);        // 32 MB  (256*64*1024)

  // sentinel-fill hs FIRST (sc1: never creates per-XCD L2 lines for hsB)
  fill_sentinel<<<2048, 256, 0, stream>>>((u32*)hsB, T_LEN * B_SZ * 512 / 4);

  cvt_f32_bf16<<<2048, 256, 0, stream>>>(inp,  inpB,  T_LEN * B_SZ * IN_D);
  cvt_f32_bf16<<<2048, 256, 0, stream>>>(Wxh,  WxhB,  G4 * IN_D);
  cvt_f32_bf16<<<2048, 256, 0, stream>>>(Whh,  WhhB,  G4 * H_D);
  cvt_f32_bf16<<<2048, 256, 0, stream>>>(Wout, WoutB, IN_D * H_D);

  // xproj = inp@Wxh^T + bxh (+ img4 at t=0), bf16 out
  gemm_bt<IN_D, 0><<<dim3(G4 / 128, 16384 / 128), 256, 0, stream>>>(
      inpB, WxhB, bxh, img, xprojB, nullptr, G4);

  lstm_rec<<<256, 256, 0, stream>>>(WhhB, xprojB, bhh, (u32*)hsB);

  // logits = hs@Wout^T + bout, f32 into d_out
  gemm_bt<H_D, 1><<<dim3(IN_D / 128, 16384 / 128), 256, 0, stream>>>(
      hsB, WoutB, bout, nullptr, nullptr, out, IN_D);

  logsoftmax_rows<<<16384, 256, 0, stream>>>(out);
}